// Round 10
// baseline (203.605 us; speedup 1.0000x reference)
//
#include <hip/hip_runtime.h>
#include <stdint.h>
#include <math.h>

typedef __attribute__((ext_vector_type(8))) __bf16 bf16x8;
typedef __attribute__((ext_vector_type(4))) float f32x4;

// ---- fp32 -> bf16 (RNE) ----
__device__ __forceinline__ unsigned short f2bf(float f) {
    unsigned u = __float_as_uint(f);
    u += 0x7FFF + ((u >> 16) & 1);
    return (unsigned short)(u >> 16);
}
__device__ __forceinline__ float bf2f(unsigned short u) {
    return __uint_as_float((unsigned)u << 16);
}

__global__ __launch_bounds__(256)
void f32_to_bf16_k(const float* __restrict__ in, unsigned short* __restrict__ out, int n4) {
    int i = blockIdx.x * blockDim.x + threadIdx.x;
    int stride = gridDim.x * blockDim.x;
    for (; i < n4; i += stride) {
        float4 v = reinterpret_cast<const float4*>(in)[i];
        ushort4 o;
        o.x = f2bf(v.x); o.y = f2bf(v.y); o.z = f2bf(v.z); o.w = f2bf(v.w);
        reinterpret_cast<ushort4*>(out)[i] = o;
    }
}

__global__ __launch_bounds__(256)
void w_convert_k(const float* __restrict__ Wq, const float* __restrict__ Wk,
                 const float* __restrict__ Wv, unsigned short* __restrict__ out, int n4) {
    const float* src = blockIdx.y == 0 ? Wq : (blockIdx.y == 1 ? Wk : Wv);
    unsigned short* dst = out + (size_t)blockIdx.y * n4 * 4;
    int i = blockIdx.x * blockDim.x + threadIdx.x;
    int stride = gridDim.x * blockDim.x;
    for (; i < n4; i += stride) {
        float4 v = reinterpret_cast<const float4*>(src)[i];
        ushort4 o;
        o.x = f2bf(v.x); o.y = f2bf(v.y); o.z = f2bf(v.z); o.w = f2bf(v.w);
        reinterpret_cast<ushort4*>(dst)[i] = o;
    }
}

__device__ __forceinline__ void gload16(const unsigned short* g, unsigned short* l) {
    __builtin_amdgcn_global_load_lds(
        (const __attribute__((address_space(1))) unsigned int*)g,
        (__attribute__((address_space(3))) unsigned int*)l, 16, 0, 0);
}

// ==== NT GEMM core: BK=32, QUAD-buffer depth-3 prefetch, counted vmcnt, XOR swizzle ====
// 128x128 tile, 256 threads (4 waves 2x2), LDS 4x(8+8)KB = 64KB -> 2 blocks/CU.
// C[m,n] = scale * sum_k A[m,k]*B[n,k];  A:[M,K], B:[N,K] row-major bf16.
// Depth-3 pipeline: tile t staged at step t-3 (~2600cy cover >> 900cy HBM latency);
// per step issue 4 loads, wait vmcnt(12/8/4/0 by tiles-remaining) -> tile t landed.
// Swizzle: 16B chunk cc of row r stored at chunk (cc ^ (r&3)); applied on global source
// (LDS dest linear for global_load_lds) and on ds_read address (involution).
// MODE 0: dense (br=work/nbx, bc=work%nbx), kmax=K.
// MODE 1: triangular job list + extra job nwg+(work>>4) when (work&15)==8.
// MODE 3: causal rows: s=work&1, pp=work>>1, col=pp&7, rp=pp>>3, row=s?15-rp:rp,
//         kmax=(row+1)*BM.
template <typename CT, int MODE>
__global__ __launch_bounds__(256, 2)
void gemm8(const unsigned short* __restrict__ A, const unsigned short* __restrict__ B,
           CT* __restrict__ C, int lda, int ldb, int ldc, int K,
           long long sA, long long sB, long long sC, float scale, int totj)
{
    constexpr int BM = 128, BN = 128;
    constexpr int FM = 4, FN = 4;

    // bijective XCD-aware work remap (m204), per z-slice
    const int nbx = gridDim.x;
    const int nwg = nbx * gridDim.y;
    const int orig = blockIdx.y * nbx + blockIdx.x;
    const int q8 = nwg >> 3, r8 = nwg & 7;
    const int xcd = orig & 7, idx = orig >> 3;
    const int work = (xcd < r8 ? xcd * (q8 + 1) : r8 * (q8 + 1) + (xcd - r8) * q8) + idx;

    A += (long long)blockIdx.z * sA;
    B += (long long)blockIdx.z * sB;
    C += (long long)blockIdx.z * sC;

    __shared__ unsigned short As[4][BM * 32];
    __shared__ unsigned short Bs[4][BN * 32];

    const int t    = threadIdx.x;
    const int lane = t & 63;
    const int wid  = t >> 6;
    const int wm   = wid >> 1, wn = wid & 1;
    const int rsel = lane & 15;
    const int gsel = lane >> 4;                  // 0..3
    const int srow = t >> 2;                     // staging row 0..63 (first chunk)
    const int swz  = ((t & 3) ^ (srow & 3)) * 8; // swizzled elem offset (row&3 invariant +64)

    auto run_tile = [&](int br, int bc, int kmax, bool first) {
        const int m0 = br * BM, n0 = bc * BN;
        f32x4 acc[FM][FN];
#pragma unroll
        for (int m = 0; m < FM; ++m)
#pragma unroll
            for (int n = 0; n < FN; ++n) acc[m][n] = (f32x4){0.f, 0.f, 0.f, 0.f};

        // hoisted staging pointers: 2 A-chunks + 2 B-chunks per thread, advance +32/tile
        const unsigned short* gpA[2];
        const unsigned short* gpB[2];
#pragma unroll
        for (int i = 0; i < 2; ++i) {
            gpA[i] = A + (long long)(m0 + srow + 64 * i) * lda + swz;
            gpB[i] = B + (long long)(n0 + srow + 64 * i) * ldb + swz;
        }
        auto stage = [&](int buf) {
            gload16(gpA[0], &As[buf][t * 8]);
            gload16(gpA[1], &As[buf][2048 + t * 8]);
            gload16(gpB[0], &Bs[buf][t * 8]);
            gload16(gpB[1], &Bs[buf][2048 + t * 8]);
            gpA[0] += 32; gpA[1] += 32; gpB[0] += 32; gpB[1] += 32;
        };

        const int nk = kmax >> 5;
        if (!first) {                            // protect LDS from previous job's readers
            __builtin_amdgcn_s_barrier();
            __builtin_amdgcn_sched_barrier(0);
        }
        stage(0);
        if (1 < nk) stage(1);
        if (2 < nk) stage(2);

        for (int kt = 0; kt < nk; ++kt) {
            const int c = kt & 3;
            __builtin_amdgcn_s_barrier();        // step kt-1 reads done -> buf (kt+3)&3 free
            __builtin_amdgcn_sched_barrier(0);
            if (kt + 3 < nk) stage((kt + 3) & 3);
            const int rem = nk - 1 - kt;         // tiles staged beyond kt still wanted in flight
            if (rem >= 3)      asm volatile("s_waitcnt vmcnt(12)" ::: "memory");
            else if (rem == 2) asm volatile("s_waitcnt vmcnt(8)"  ::: "memory");
            else if (rem == 1) asm volatile("s_waitcnt vmcnt(4)"  ::: "memory");
            else               asm volatile("s_waitcnt vmcnt(0)"  ::: "memory");
            __builtin_amdgcn_s_barrier();        // collective: tile kt fully in LDS
            __builtin_amdgcn_sched_barrier(0);

            bf16x8 aF[FM], bF[FN];
#pragma unroll
            for (int m = 0; m < FM; ++m) {
                int r = wm * (FM * 16) + m * 16 + rsel;
                aF[m] = *reinterpret_cast<const bf16x8*>(
                    &As[c][r * 32 + ((gsel ^ (r & 3)) * 8)]);
            }
#pragma unroll
            for (int n = 0; n < FN; ++n) {
                int rb = wn * (FN * 16) + n * 16 + rsel;
                bF[n] = *reinterpret_cast<const bf16x8*>(
                    &Bs[c][rb * 32 + ((gsel ^ (rb & 3)) * 8)]);
            }

            __builtin_amdgcn_s_setprio(1);
#pragma unroll
            for (int m = 0; m < FM; ++m)
#pragma unroll
                for (int n = 0; n < FN; ++n)
                    acc[m][n] = __builtin_amdgcn_mfma_f32_16x16x32_bf16(
                        aF[m], bF[n], acc[m][n], 0, 0, 0);
            __builtin_amdgcn_s_setprio(0);
        }

        // epilogue: D[row][col], col = lane&15, row = (lane>>4)*4 + i  (m89-verified)
        const int rowl = gsel * 4;
#pragma unroll
        for (int m = 0; m < FM; ++m) {
#pragma unroll
            for (int n = 0; n < FN; ++n) {
#pragma unroll
                for (int i = 0; i < 4; ++i) {
                    int r  = m0 + wm * (FM * 16) + m * 16 + rowl + i;
                    int cI = n0 + wn * (FN * 16) + n * 16 + rsel;
                    float v = acc[m][n][i] * scale;
                    if constexpr (sizeof(CT) == 2)
                        ((unsigned short*)C)[(long long)r * ldc + cI] = f2bf(v);
                    else
                        ((float*)C)[(long long)r * ldc + cI] = v;
                }
            }
        }
    };

    auto tri = [&](int w, int& br, int& bc) {
        int rr = (int)((sqrtf(8.0f * (float)w + 1.0f) - 1.0f) * 0.5f);
        while ((rr + 1) * (rr + 2) / 2 <= w) ++rr;
        while (rr * (rr + 1) / 2 > w) --rr;
        br = rr; bc = w - rr * (rr + 1) / 2;
    };

    if constexpr (MODE == 0) {
        run_tile(work / nbx, work % nbx, K, true);
    } else if constexpr (MODE == 1) {
        int br, bc;
        tri(work, br, bc);
        run_tile(br, bc, K, true);
        const int e = work >> 4;
        if ((work & 15) == 8 && nwg + e < totj) {
            tri(nwg + e, br, bc);
            run_tile(br, bc, K, false);
        }
    } else {
        const int s = work & 1, pp = work >> 1;
        const int col = pp & 7, rp = pp >> 3;
        const int row = s ? 15 - rp : rp;
        run_tile(row, col, (row + 1) * BM, true);
    }
}

// ---- causal row softmax: bf16 scores in, bf16 P out, LDS-cached single read ----
__device__ __forceinline__ float waveMax(float v) {
#pragma unroll
    for (int o = 32; o > 0; o >>= 1) v = fmaxf(v, __shfl_xor(v, o, 64));
    return v;
}
__device__ __forceinline__ float waveSum(float v) {
#pragma unroll
    for (int o = 32; o > 0; o >>= 1) v += __shfl_xor(v, o, 64);
    return v;
}

__global__ __launch_bounds__(256)
void softmax_causal(const unsigned short* __restrict__ S, unsigned short* __restrict__ P,
                    int Slen) {
    __shared__ float e[2048];
    __shared__ float red[4];
    long long row = blockIdx.x;                 // b*Slen + q
    int q = (int)(row % Slen);
    const unsigned short* srow = S + row * (long long)Slen;
    unsigned short* prow = P + row * (long long)Slen;
    int len = q + 1;
    int t = threadIdx.x;

    int n8 = len >> 3;
    float mx = -3.0e38f;
    for (int i = t; i < n8; i += 256) {
        uint4 v = reinterpret_cast<const uint4*>(srow)[i];
        float f0 = __uint_as_float(v.x << 16), f1 = __uint_as_float(v.x & 0xffff0000u);
        float f2 = __uint_as_float(v.y << 16), f3 = __uint_as_float(v.y & 0xffff0000u);
        float f4 = __uint_as_float(v.z << 16), f5 = __uint_as_float(v.z & 0xffff0000u);
        float f6 = __uint_as_float(v.w << 16), f7 = __uint_as_float(v.w & 0xffff0000u);
        e[8 * i + 0] = f0; e[8 * i + 1] = f1; e[8 * i + 2] = f2; e[8 * i + 3] = f3;
        e[8 * i + 4] = f4; e[8 * i + 5] = f5; e[8 * i + 6] = f6; e[8 * i + 7] = f7;
        mx = fmaxf(mx, fmaxf(fmaxf(fmaxf(f0, f1), fmaxf(f2, f3)),
                             fmaxf(fmaxf(f4, f5), fmaxf(f6, f7))));
    }
    if (t < (len & 7)) {
        float v = bf2f(srow[n8 * 8 + t]);
        e[n8 * 8 + t] = v;
        mx = fmaxf(mx, v);
    }
    mx = waveMax(mx);
    if ((t & 63) == 0) red[t >> 6] = mx;
    __syncthreads();
    mx = fmaxf(fmaxf(red[0], red[1]), fmaxf(red[2], red[3]));

    float sum = 0.f;
    for (int k = t; k < len; k += 256) {
        float v = __expf(e[k] - mx);
        e[k] = v;
        sum += v;
    }
    sum = waveSum(sum);
    __syncthreads();
    if ((t & 63) == 0) red[t >> 6] = sum;
    __syncthreads();
    sum = red[0] + red[1] + red[2] + red[3];
    float inv = 1.0f / sum;

    int wlim = ((q >> 7) + 1) << 7;             // PV (BM=128) reads only k < roundup(len,128)
    __syncthreads();                            // e[] writes visible
    for (int i = t; i < (wlim >> 2); i += 256) {
        int k = 4 * i;
        ushort4 o;
        o.x = (k + 0 < len) ? f2bf(e[k + 0] * inv) : (unsigned short)0;
        o.y = (k + 1 < len) ? f2bf(e[k + 1] * inv) : (unsigned short)0;
        o.z = (k + 2 < len) ? f2bf(e[k + 2] * inv) : (unsigned short)0;
        o.w = (k + 3 < len) ? f2bf(e[k + 3] * inv) : (unsigned short)0;
        reinterpret_cast<ushort4*>(prow)[i] = o;
    }
}

extern "C" void kernel_launch(void* const* d_in, const int* in_sizes, int n_in,
                              void* d_out, int out_size, void* d_ws, size_t ws_size,
                              hipStream_t stream) {
    const int B = 4, S = 2048, D = 1024;
    const float* X  = (const float*)d_in[0];
    const float* Wq = (const float*)d_in[1];
    const float* Wk = (const float*)d_in[2];
    const float* Wv = (const float*)d_in[3];
    float* out = (float*)d_out;

    char* ws = (char*)d_ws;
    unsigned short* Xb  = (unsigned short*)ws; ws += (size_t)B * S * D * 2;
    unsigned short* Wqb = (unsigned short*)ws; ws += (size_t)D * D * 2;  // Wq,Wk,Wv contiguous
    unsigned short* Wkb = (unsigned short*)ws; ws += (size_t)D * D * 2;
    unsigned short* Wvb = (unsigned short*)ws; ws += (size_t)D * D * 2;
    unsigned short* Qb  = (unsigned short*)ws; ws += (size_t)B * S * D * 2;  // Q,K contiguous
    unsigned short* Kb  = (unsigned short*)ws; ws += (size_t)B * S * D * 2;
    unsigned short* Vt  = (unsigned short*)ws; ws += (size_t)B * S * D * 2;  // [b][e][k]
    unsigned short* Sc  = (unsigned short*)ws; ws += (size_t)B * S * S * 2;  // bf16 scores
    unsigned short* P   = (unsigned short*)ws; ws += (size_t)B * S * S * 2;

    f32_to_bf16_k<<<2048, 256, 0, stream>>>(X, Xb, B * S * D / 4);
    w_convert_k<<<dim3(512, 3), 256, 0, stream>>>(Wq, Wk, Wv, Wqb, D * D / 4);

    dim3 blk(256);
    // Q and K in one dispatch: grid (8, 64, 2) = 1024 blocks, MODE 0
    gemm8<unsigned short, 0><<<dim3(D / 128, B * S / 128, 2), blk, 0, stream>>>(
        Xb, Wqb, Qb, D, D, D, D, 0, (long long)D * D, (long long)B * S * D, 1.0f, 0);

    // Vt[b] = Wv @ Xb[b]^T : grid (16, 8, 4) = 512 blocks, MODE 0
    gemm8<unsigned short, 0><<<dim3(S / 128, D / 128, B), blk, 0, stream>>>(
        Wvb, Xb, Vt, D, D, S, D, 0, (long long)S * D, (long long)D * S, 1.0f, 0);

    // scores = (Q K^T)/32 as bf16 : 136 tri-tiles/batch over 128 blocks (8 spread extras)
    gemm8<unsigned short, 1><<<dim3(8, 16, B), blk, 0, stream>>>(
        Qb, Kb, Sc, D, D, S, D, (long long)S * D, (long long)S * D, (long long)S * S,
        0.03125f, 136);

    softmax_causal<<<B * S, 256, 0, stream>>>(Sc, P, S);

    // out = P @ Vt^T : 512 single-tile blocks, complementary row interleave, MODE 3
    gemm8<float, 3><<<dim3(8, 16, B), blk, 0, stream>>>(
        P, Vt, out, S, S, D, S, (long long)S * S, (long long)D * S, (long long)S * D,
        1.0f, 0);
}

// Round 11
// 172.961 us; speedup vs baseline: 1.1772x; 1.1772x over previous
//
#include <hip/hip_runtime.h>
#include <stdint.h>
#include <math.h>

typedef __attribute__((ext_vector_type(8))) __bf16 bf16x8;
typedef __attribute__((ext_vector_type(4))) float f32x4;

// ---- fp32 -> bf16 (RNE) ----
__device__ __forceinline__ unsigned short f2bf(float f) {
    unsigned u = __float_as_uint(f);
    u += 0x7FFF + ((u >> 16) & 1);
    return (unsigned short)(u >> 16);
}
__device__ __forceinline__ float bf2f(unsigned short u) {
    return __uint_as_float((unsigned)u << 16);
}

// merged convert: y=0 -> X (n4x items), y=1..3 -> Wq/Wk/Wv (n4w items each)
__global__ __launch_bounds__(256)
void convert_all_k(const float* __restrict__ X, const float* __restrict__ Wq,
                   const float* __restrict__ Wk, const float* __restrict__ Wv,
                   unsigned short* __restrict__ Xb, unsigned short* __restrict__ Wb,
                   int n4x, int n4w) {
    const float* src;
    unsigned short* dst;
    int n4;
    if (blockIdx.y == 0) { src = X; dst = Xb; n4 = n4x; }
    else {
        src = blockIdx.y == 1 ? Wq : (blockIdx.y == 2 ? Wk : Wv);
        dst = Wb + (size_t)(blockIdx.y - 1) * n4w * 4;
        n4 = n4w;
    }
    int i = blockIdx.x * blockDim.x + threadIdx.x;
    int stride = gridDim.x * blockDim.x;
    for (; i < n4; i += stride) {
        float4 v = reinterpret_cast<const float4*>(src)[i];
        ushort4 o;
        o.x = f2bf(v.x); o.y = f2bf(v.y); o.z = f2bf(v.z); o.w = f2bf(v.w);
        reinterpret_cast<ushort4*>(dst)[i] = o;
    }
}

__device__ __forceinline__ void gload16(const unsigned short* g, unsigned short* l) {
    __builtin_amdgcn_global_load_lds(
        (const __attribute__((address_space(1))) unsigned int*)g,
        (__attribute__((address_space(3))) unsigned int*)l, 16, 0, 0);
}

// ============ NT GEMM core (round-9 proven): BK=64, counted-vmcnt dbuf, XOR swizzle ====
// 128x128 tile, 256 threads (4 waves 2x2), LDS 64KB -> 2 blocks/CU.
// C[m,n] = scale * sum_k A[m,k]*B[n,k];  A:[M,K], B:[N,K] row-major bf16.
// Per-CU throughput (measured r8-r10): 1.38 block-steps/us paired, 0.72 solo ->
// co-resident blocks MUST have equal K-extent for full-rate execution.
// MODE 0: dense grid (br=work/nbx, bc=work%nbx), kmax=K.
// MODE 1: triangular job list; + extra job nwg+(work>>4) when (work&15)==8.
// MODE 3: balanced causal rows: chunk=work>>4 holds rows {chunk, 15-chunk};
//         adjacent works share a row -> co-resident pairs have equal nk.
template <typename CT, int MODE>
__global__ __launch_bounds__(256, 2)
void gemm8(const unsigned short* __restrict__ A, const unsigned short* __restrict__ B,
           CT* __restrict__ C, int lda, int ldb, int ldc, int K,
           long long sA, long long sB, long long sC, float scale, int totj)
{
    constexpr int BM = 128, BN = 128;
    constexpr int FM = 4, FN = 4;

    // bijective XCD-aware work remap (m204), per z-slice
    const int nbx = gridDim.x;
    const int nwg = nbx * gridDim.y;
    const int orig = blockIdx.y * nbx + blockIdx.x;
    const int q8 = nwg >> 3, r8 = nwg & 7;
    const int xcd = orig & 7, idx = orig >> 3;
    const int work = (xcd < r8 ? xcd * (q8 + 1) : r8 * (q8 + 1) + (xcd - r8) * q8) + idx;

    A += (long long)blockIdx.z * sA;
    B += (long long)blockIdx.z * sB;
    C += (long long)blockIdx.z * sC;

    __shared__ unsigned short As[2][BM * 64];
    __shared__ unsigned short Bs[2][BN * 64];

    const int t    = threadIdx.x;
    const int lane = t & 63;
    const int wid  = t >> 6;
    const int wm   = wid >> 1, wn = wid & 1;
    const int rsel = lane & 15;
    const int gsel = lane >> 4;                  // 0..3
    const int srow = t >> 3;                     // staging row 0..31 (chunk 0)
    const int swz  = ((t & 7) ^ (srow & 7)) * 8; // swizzled element offset (ks-invariant)

    auto run_tile = [&](int br, int bc, int kmax, bool first) {
        const int m0 = br * BM, n0 = bc * BN;
        f32x4 acc[FM][FN];
#pragma unroll
        for (int m = 0; m < FM; ++m)
#pragma unroll
            for (int n = 0; n < FN; ++n) acc[m][n] = (f32x4){0.f, 0.f, 0.f, 0.f};

        // hoisted staging pointers: 4 A-rows + 4 B-rows per thread, advance +64/tile
        const unsigned short* gpA[4];
        const unsigned short* gpB[4];
#pragma unroll
        for (int i = 0; i < 4; ++i) {
            gpA[i] = A + (long long)(m0 + srow + 32 * i) * lda + swz;
            gpB[i] = B + (long long)(n0 + srow + 32 * i) * ldb + swz;
        }

        auto stage = [&](int buf) {
#pragma unroll
            for (int i = 0; i < 4; ++i)
                gload16(gpA[i], &As[buf][i * 2048 + t * 8]);
#pragma unroll
            for (int i = 0; i < 4; ++i)
                gload16(gpB[i], &Bs[buf][i * 2048 + t * 8]);
#pragma unroll
            for (int i = 0; i < 4; ++i) { gpA[i] += 64; gpB[i] += 64; }
        };

        const int nk = kmax >> 6;
        if (!first) {                            // protect LDS from previous job's readers
            __builtin_amdgcn_s_barrier();
            __builtin_amdgcn_sched_barrier(0);
        }
        stage(0);

        for (int kt = 0; kt < nk; ++kt) {
            const int c = kt & 1;
            __builtin_amdgcn_s_barrier();        // prev compute done -> overwrite c^1 ok
            __builtin_amdgcn_sched_barrier(0);
            if (kt + 1 < nk) {
                stage(c ^ 1);                    // tile t+1 loads stay in flight
                asm volatile("s_waitcnt vmcnt(8)" ::: "memory");  // tile t fully landed
            } else {
                asm volatile("s_waitcnt vmcnt(0)" ::: "memory");
            }
            __builtin_amdgcn_s_barrier();        // collective guarantee for buf c
            __builtin_amdgcn_sched_barrier(0);

            bf16x8 aF[FM][2], bF[FN][2];
#pragma unroll
            for (int m = 0; m < FM; ++m)
#pragma unroll
                for (int ks = 0; ks < 2; ++ks) {
                    int r  = wm * (FM * 16) + m * 16 + rsel;
                    int cc = ks * 4 + gsel;
                    aF[m][ks] = *reinterpret_cast<const bf16x8*>(
                        &As[c][r * 64 + ((cc ^ (r & 7)) * 8)]);
                }
#pragma unroll
            for (int n = 0; n < FN; ++n)
#pragma unroll
                for (int ks = 0; ks < 2; ++ks) {
                    int rb = wn * (FN * 16) + n * 16 + rsel;
                    int cc = ks * 4 + gsel;
                    bF[n][ks] = *reinterpret_cast<const bf16x8*>(
                        &Bs[c][rb * 64 + ((cc ^ (rb & 7)) * 8)]);
                }

            __builtin_amdgcn_s_setprio(1);
#pragma unroll
            for (int m = 0; m < FM; ++m)
#pragma unroll
                for (int n = 0; n < FN; ++n)
#pragma unroll
                    for (int ks = 0; ks < 2; ++ks)
                        acc[m][n] = __builtin_amdgcn_mfma_f32_16x16x32_bf16(
                            aF[m][ks], bF[n][ks], acc[m][n], 0, 0, 0);
            __builtin_amdgcn_s_setprio(0);
        }

        // epilogue: D[row][col], col = lane&15, row = (lane>>4)*4 + i  (m89-verified)
        const int rowl = gsel * 4;
#pragma unroll
        for (int m = 0; m < FM; ++m) {
#pragma unroll
            for (int n = 0; n < FN; ++n) {
#pragma unroll
                for (int i = 0; i < 4; ++i) {
                    int r  = m0 + wm * (FM * 16) + m * 16 + rowl + i;
                    int cI = n0 + wn * (FN * 16) + n * 16 + rsel;
                    float v = acc[m][n][i] * scale;
                    if constexpr (sizeof(CT) == 2)
                        ((unsigned short*)C)[(long long)r * ldc + cI] = f2bf(v);
                    else
                        ((float*)C)[(long long)r * ldc + cI] = v;
                }
            }
        }
    };

    auto tri = [&](int w, int& br, int& bc) {
        int rr = (int)((sqrtf(8.0f * (float)w + 1.0f) - 1.0f) * 0.5f);
        while ((rr + 1) * (rr + 2) / 2 <= w) ++rr;
        while (rr * (rr + 1) / 2 > w) --rr;
        br = rr; bc = w - rr * (rr + 1) / 2;
    };

    if constexpr (MODE == 0) {
        run_tile(work / nbx, work % nbx, K, true);
    } else if constexpr (MODE == 1) {
        int br, bc;
        tri(work, br, bc);
        run_tile(br, bc, K, true);
        const int e = work >> 4;
        if ((work & 15) == 8 && nwg + e < totj) {
            tri(nwg + e, br, bc);
            run_tile(br, bc, K, false);
        }
    } else {
        const int chunk = work >> 4;             // 0..7 (= XCD of this work)
        const int lo    = work & 15;
        const int col   = work & 7;
        const int row   = (lo < 8) ? chunk : 15 - chunk;
        run_tile(row, col, (row + 1) * BM, true);
    }
}

// ---- causal row softmax: bf16 scores in, bf16 P out, LDS-cached single read ----
__device__ __forceinline__ float waveMax(float v) {
#pragma unroll
    for (int o = 32; o > 0; o >>= 1) v = fmaxf(v, __shfl_xor(v, o, 64));
    return v;
}
__device__ __forceinline__ float waveSum(float v) {
#pragma unroll
    for (int o = 32; o > 0; o >>= 1) v += __shfl_xor(v, o, 64);
    return v;
}

__global__ __launch_bounds__(256)
void softmax_causal(const unsigned short* __restrict__ S, unsigned short* __restrict__ P,
                    int Slen) {
    __shared__ float e[2048];
    __shared__ float red[4];
    long long row = blockIdx.x;                 // b*Slen + q
    int q = (int)(row % Slen);
    const unsigned short* srow = S + row * (long long)Slen;
    unsigned short* prow = P + row * (long long)Slen;
    int len = q + 1;
    int t = threadIdx.x;

    int n8 = len >> 3;
    float mx = -3.0e38f;
    for (int i = t; i < n8; i += 256) {
        uint4 v = reinterpret_cast<const uint4*>(srow)[i];
        float f0 = __uint_as_float(v.x << 16), f1 = __uint_as_float(v.x & 0xffff0000u);
        float f2 = __uint_as_float(v.y << 16), f3 = __uint_as_float(v.y & 0xffff0000u);
        float f4 = __uint_as_float(v.z << 16), f5 = __uint_as_float(v.z & 0xffff0000u);
        float f6 = __uint_as_float(v.w << 16), f7 = __uint_as_float(v.w & 0xffff0000u);
        e[8 * i + 0] = f0; e[8 * i + 1] = f1; e[8 * i + 2] = f2; e[8 * i + 3] = f3;
        e[8 * i + 4] = f4; e[8 * i + 5] = f5; e[8 * i + 6] = f6; e[8 * i + 7] = f7;
        mx = fmaxf(mx, fmaxf(fmaxf(fmaxf(f0, f1), fmaxf(f2, f3)),
                             fmaxf(fmaxf(f4, f5), fmaxf(f6, f7))));
    }
    if (t < (len & 7)) {
        float v = bf2f(srow[n8 * 8 + t]);
        e[n8 * 8 + t] = v;
        mx = fmaxf(mx, v);
    }
    mx = waveMax(mx);
    if ((t & 63) == 0) red[t >> 6] = mx;
    __syncthreads();
    mx = fmaxf(fmaxf(red[0], red[1]), fmaxf(red[2], red[3]));

    float sum = 0.f;
    for (int k = t; k < len; k += 256) {
        float v = __expf(e[k] - mx);
        e[k] = v;
        sum += v;
    }
    sum = waveSum(sum);
    __syncthreads();
    if ((t & 63) == 0) red[t >> 6] = sum;
    __syncthreads();
    sum = red[0] + red[1] + red[2] + red[3];
    float inv = 1.0f / sum;

    int wlim = ((q >> 7) + 1) << 7;             // PV (BM=128) reads only k < roundup(len,128)
    __syncthreads();                            // e[] writes visible
    for (int i = t; i < (wlim >> 2); i += 256) {
        int k = 4 * i;
        ushort4 o;
        o.x = (k + 0 < len) ? f2bf(e[k + 0] * inv) : (unsigned short)0;
        o.y = (k + 1 < len) ? f2bf(e[k + 1] * inv) : (unsigned short)0;
        o.z = (k + 2 < len) ? f2bf(e[k + 2] * inv) : (unsigned short)0;
        o.w = (k + 3 < len) ? f2bf(e[k + 3] * inv) : (unsigned short)0;
        reinterpret_cast<ushort4*>(prow)[i] = o;
    }
}

extern "C" void kernel_launch(void* const* d_in, const int* in_sizes, int n_in,
                              void* d_out, int out_size, void* d_ws, size_t ws_size,
                              hipStream_t stream) {
    const int B = 4, S = 2048, D = 1024;
    const float* X  = (const float*)d_in[0];
    const float* Wq = (const float*)d_in[1];
    const float* Wk = (const float*)d_in[2];
    const float* Wv = (const float*)d_in[3];
    float* out = (float*)d_out;

    char* ws = (char*)d_ws;
    unsigned short* Xb  = (unsigned short*)ws; ws += (size_t)B * S * D * 2;
    unsigned short* Wqb = (unsigned short*)ws; ws += (size_t)D * D * 2;  // Wq,Wk,Wv contiguous
    unsigned short* Wkb = (unsigned short*)ws; ws += (size_t)D * D * 2;
    unsigned short* Wvb = (unsigned short*)ws; ws += (size_t)D * D * 2;
    unsigned short* Qb  = (unsigned short*)ws; ws += (size_t)B * S * D * 2;  // Q,K contiguous
    unsigned short* Kb  = (unsigned short*)ws; ws += (size_t)B * S * D * 2;
    unsigned short* Vt  = (unsigned short*)ws; ws += (size_t)B * S * D * 2;  // [b][e][k]
    unsigned short* Sc  = (unsigned short*)ws; ws += (size_t)B * S * S * 2;  // bf16 scores
    unsigned short* P   = (unsigned short*)ws; ws += (size_t)B * S * S * 2;

    // converts merged into one dispatch
    convert_all_k<<<dim3(2048, 4), 256, 0, stream>>>(
        X, Wq, Wk, Wv, Xb, Wqb, B * S * D / 4, D * D / 4);

    dim3 blk(256);
    // Q and K in one dispatch: grid (8, 64, 2) = 1024 blocks, MODE 0
    gemm8<unsigned short, 0><<<dim3(D / 128, B * S / 128, 2), blk, 0, stream>>>(
        Xb, Wqb, Qb, D, D, D, D, 0, (long long)D * D, (long long)B * S * D, 1.0f, 0);

    // Vt[b] = Wv @ Xb[b]^T : grid (16, 8, 4) = 512 blocks, MODE 0
    gemm8<unsigned short, 0><<<dim3(S / 128, D / 128, B), blk, 0, stream>>>(
        Wvb, Xb, Vt, D, D, S, D, 0, (long long)S * D, (long long)D * S, 1.0f, 0);

    // scores = (Q K^T)/32 as bf16 : 136 tri-tiles/batch over 128 blocks (8 spread extras)
    gemm8<unsigned short, 1><<<dim3(8, 16, B), blk, 0, stream>>>(
        Qb, Kb, Sc, D, D, S, D, (long long)S * D, (long long)S * D, (long long)S * S,
        0.03125f, 136);

    softmax_causal<<<B * S, 256, 0, stream>>>(Sc, P, S);

    // out = P @ Vt^T : 512 blocks, balanced-pair causal rows (MODE 3)
    gemm8<float, 3><<<dim3(8, 16, B), blk, 0, stream>>>(
        P, Vt, out, S, S, D, S, (long long)S * S, (long long)D * S, (long long)S * D,
        1.0f, 0);
}

// Round 12
// 169.529 us; speedup vs baseline: 1.2010x; 1.0202x over previous
//
#include <hip/hip_runtime.h>
#include <stdint.h>
#include <math.h>

typedef __attribute__((ext_vector_type(8))) __bf16 bf16x8;
typedef __attribute__((ext_vector_type(4))) float f32x4;

// ---- fp32 -> bf16 (RNE) ----
__device__ __forceinline__ unsigned short f2bf(float f) {
    unsigned u = __float_as_uint(f);
    u += 0x7FFF + ((u >> 16) & 1);
    return (unsigned short)(u >> 16);
}
__device__ __forceinline__ float bf2f(unsigned short u) {
    return __uint_as_float((unsigned)u << 16);
}

// ---- tiled transpose-convert ----
// z=0..3: X[b] -> Xb[b] (plain) + XbT[b] (transposed, [e][s])
// z=4: Wq -> WqT ([i][e]);  z=5: Wk -> WkT;  z=6: Wv -> Wvb (plain)
// All sources have 1024 columns. 64x64 f32 tile via LDS for the transposed path.
__global__ __launch_bounds__(256)
void convt_k(const float* __restrict__ X, const float* __restrict__ Wq,
             const float* __restrict__ Wk, const float* __restrict__ Wv,
             unsigned short* __restrict__ Xb, unsigned short* __restrict__ XbT,
             unsigned short* __restrict__ WqT, unsigned short* __restrict__ WkT,
             unsigned short* __restrict__ Wvb) {
    const int S = 2048, D = 1024;
    const int z = blockIdx.z;
    const float* src;
    unsigned short* dstP = nullptr;
    unsigned short* dstT = nullptr;
    int rows;
    if (z < 4)      { src = X + (size_t)z * S * D; dstP = Xb + (size_t)z * S * D;
                      dstT = XbT + (size_t)z * D * S; rows = S; }
    else if (z == 4){ src = Wq; dstT = WqT; rows = D; }
    else if (z == 5){ src = Wk; dstT = WkT; rows = D; }
    else            { src = Wv; dstP = Wvb; rows = D; }
    const int r0 = blockIdx.y * 64, c0 = blockIdx.x * 64;
    if (r0 >= rows) return;

    __shared__ float tile[64][65];
    const int t = threadIdx.x;
    const int tr = t >> 4;           // 0..15
    const int tc4 = t & 15;          // float4 col 0..15
#pragma unroll
    for (int p = 0; p < 4; ++p) {
        int r = p * 16 + tr;
        float4 v = *reinterpret_cast<const float4*>(&src[(size_t)(r0 + r) * 1024 + c0 + tc4 * 4]);
        if (dstP) {
            ushort4 o; o.x = f2bf(v.x); o.y = f2bf(v.y); o.z = f2bf(v.z); o.w = f2bf(v.w);
            *reinterpret_cast<ushort4*>(&dstP[(size_t)(r0 + r) * 1024 + c0 + tc4 * 4]) = o;
        }
        if (dstT) {
            tile[r][tc4 * 4 + 0] = v.x; tile[r][tc4 * 4 + 1] = v.y;
            tile[r][tc4 * 4 + 2] = v.z; tile[r][tc4 * 4 + 3] = v.w;
        }
    }
    if (!dstT) return;
    __syncthreads();
    const int ldT = rows;
#pragma unroll
    for (int p = 0; p < 4; ++p) {
        int c = p * 16 + tr;
        ushort4 o;
        o.x = f2bf(tile[tc4 * 4 + 0][c]);
        o.y = f2bf(tile[tc4 * 4 + 1][c]);
        o.z = f2bf(tile[tc4 * 4 + 2][c]);
        o.w = f2bf(tile[tc4 * 4 + 3][c]);
        *reinterpret_cast<ushort4*>(&dstT[(size_t)(c0 + c) * ldT + r0 + tc4 * 4]) = o;
    }
}

// ---- reduce 4 fp32 partial slabs -> bf16 ----
__global__ __launch_bounds__(256)
void reduce4_k(const float* __restrict__ p, unsigned short* __restrict__ o, int n4) {
    const int slab = 1024 * 1024 / 4;
    int i = blockIdx.x * blockDim.x + threadIdx.x;
    int stride = gridDim.x * blockDim.x;
    for (; i < n4; i += stride) {
        float4 a = reinterpret_cast<const float4*>(p)[i];
        float4 b = reinterpret_cast<const float4*>(p)[i + slab];
        float4 c = reinterpret_cast<const float4*>(p)[i + 2 * slab];
        float4 d = reinterpret_cast<const float4*>(p)[i + 3 * slab];
        ushort4 u;
        u.x = f2bf(a.x + b.x + c.x + d.x);
        u.y = f2bf(a.y + b.y + c.y + d.y);
        u.z = f2bf(a.z + b.z + c.z + d.z);
        u.w = f2bf(a.w + b.w + c.w + d.w);
        reinterpret_cast<ushort4*>(o)[i] = u;
    }
}

__device__ __forceinline__ void gload16(const unsigned short* g, unsigned short* l) {
    __builtin_amdgcn_global_load_lds(
        (const __attribute__((address_space(1))) unsigned int*)g,
        (__attribute__((address_space(3))) unsigned int*)l, 16, 0, 0);
}

// ============ NT GEMM core (r9/r11 proven): BK=64, counted-vmcnt dbuf, XOR swizzle ====
// 128x128 tile, 256 threads (4 waves 2x2), LDS 64KB -> 2 blocks/CU.
// C[m,n] = scale * sum_k A[m,k]*B[n,k];  A:[M,K], B:[N,K] row-major bf16.
// MODE 0: dense grid (br=work/nbx, bc=work%nbx), kmax=K.
// MODE 1: triangular job list; + extra job nwg+(work>>4) when (work&15)==8.
// MODE 3: balanced causal rows: chunk=work>>4 holds rows {chunk,15-chunk}; kmax=(row+1)*BM.
template <typename CT, int MODE>
__global__ __launch_bounds__(256, 2)
void gemm8(const unsigned short* __restrict__ A, const unsigned short* __restrict__ B,
           CT* __restrict__ C, int lda, int ldb, int ldc, int K,
           long long sA, long long sB, long long sC, float scale, int totj)
{
    constexpr int BM = 128, BN = 128;
    constexpr int FM = 4, FN = 4;

    // bijective XCD-aware work remap (m204), per z-slice
    const int nbx = gridDim.x;
    const int nwg = nbx * gridDim.y;
    const int orig = blockIdx.y * nbx + blockIdx.x;
    const int q8 = nwg >> 3, r8 = nwg & 7;
    const int xcd = orig & 7, idx = orig >> 3;
    const int work = (xcd < r8 ? xcd * (q8 + 1) : r8 * (q8 + 1) + (xcd - r8) * q8) + idx;

    A += (long long)blockIdx.z * sA;
    B += (long long)blockIdx.z * sB;
    C += (long long)blockIdx.z * sC;

    __shared__ unsigned short As[2][BM * 64];
    __shared__ unsigned short Bs[2][BN * 64];

    const int t    = threadIdx.x;
    const int lane = t & 63;
    const int wid  = t >> 6;
    const int wm   = wid >> 1, wn = wid & 1;
    const int rsel = lane & 15;
    const int gsel = lane >> 4;                  // 0..3
    const int srow = t >> 3;                     // staging row 0..31 (chunk 0)
    const int swz  = ((t & 7) ^ (srow & 7)) * 8; // swizzled element offset (ks-invariant)

    auto run_tile = [&](int br, int bc, int kmax, bool first) {
        const int m0 = br * BM, n0 = bc * BN;
        f32x4 acc[FM][FN];
#pragma unroll
        for (int m = 0; m < FM; ++m)
#pragma unroll
            for (int n = 0; n < FN; ++n) acc[m][n] = (f32x4){0.f, 0.f, 0.f, 0.f};

        const unsigned short* gpA[4];
        const unsigned short* gpB[4];
#pragma unroll
        for (int i = 0; i < 4; ++i) {
            gpA[i] = A + (long long)(m0 + srow + 32 * i) * lda + swz;
            gpB[i] = B + (long long)(n0 + srow + 32 * i) * ldb + swz;
        }

        auto stage = [&](int buf) {
#pragma unroll
            for (int i = 0; i < 4; ++i)
                gload16(gpA[i], &As[buf][i * 2048 + t * 8]);
#pragma unroll
            for (int i = 0; i < 4; ++i)
                gload16(gpB[i], &Bs[buf][i * 2048 + t * 8]);
#pragma unroll
            for (int i = 0; i < 4; ++i) { gpA[i] += 64; gpB[i] += 64; }
        };

        const int nk = kmax >> 6;
        if (!first) {
            __builtin_amdgcn_s_barrier();
            __builtin_amdgcn_sched_barrier(0);
        }
        stage(0);

        for (int kt = 0; kt < nk; ++kt) {
            const int c = kt & 1;
            __builtin_amdgcn_s_barrier();        // prev compute done -> overwrite c^1 ok
            __builtin_amdgcn_sched_barrier(0);
            if (kt + 1 < nk) {
                stage(c ^ 1);                    // tile t+1 loads stay in flight
                asm volatile("s_waitcnt vmcnt(8)" ::: "memory");  // tile t fully landed
            } else {
                asm volatile("s_waitcnt vmcnt(0)" ::: "memory");
            }
            __builtin_amdgcn_s_barrier();        // collective guarantee for buf c
            __builtin_amdgcn_sched_barrier(0);

            bf16x8 aF[FM][2], bF[FN][2];
#pragma unroll
            for (int m = 0; m < FM; ++m)
#pragma unroll
                for (int ks = 0; ks < 2; ++ks) {
                    int r  = wm * (FM * 16) + m * 16 + rsel;
                    int cc = ks * 4 + gsel;
                    aF[m][ks] = *reinterpret_cast<const bf16x8*>(
                        &As[c][r * 64 + ((cc ^ (r & 7)) * 8)]);
                }
#pragma unroll
            for (int n = 0; n < FN; ++n)
#pragma unroll
                for (int ks = 0; ks < 2; ++ks) {
                    int rb = wn * (FN * 16) + n * 16 + rsel;
                    int cc = ks * 4 + gsel;
                    bF[n][ks] = *reinterpret_cast<const bf16x8*>(
                        &Bs[c][rb * 64 + ((cc ^ (rb & 7)) * 8)]);
                }

            __builtin_amdgcn_s_setprio(1);
#pragma unroll
            for (int m = 0; m < FM; ++m)
#pragma unroll
                for (int n = 0; n < FN; ++n)
#pragma unroll
                    for (int ks = 0; ks < 2; ++ks)
                        acc[m][n] = __builtin_amdgcn_mfma_f32_16x16x32_bf16(
                            aF[m][ks], bF[n][ks], acc[m][n], 0, 0, 0);
            __builtin_amdgcn_s_setprio(0);
        }

        // epilogue: D[row][col], col = lane&15, row = (lane>>4)*4 + i  (m89-verified)
        const int rowl = gsel * 4;
#pragma unroll
        for (int m = 0; m < FM; ++m) {
#pragma unroll
            for (int n = 0; n < FN; ++n) {
#pragma unroll
                for (int i = 0; i < 4; ++i) {
                    int r  = m0 + wm * (FM * 16) + m * 16 + rowl + i;
                    int cI = n0 + wn * (FN * 16) + n * 16 + rsel;
                    float v = acc[m][n][i] * scale;
                    if constexpr (sizeof(CT) == 2)
                        ((unsigned short*)C)[(long long)r * ldc + cI] = f2bf(v);
                    else
                        ((float*)C)[(long long)r * ldc + cI] = v;
                }
            }
        }
    };

    auto tri = [&](int w, int& br, int& bc) {
        int rr = (int)((sqrtf(8.0f * (float)w + 1.0f) - 1.0f) * 0.5f);
        while ((rr + 1) * (rr + 2) / 2 <= w) ++rr;
        while (rr * (rr + 1) / 2 > w) --rr;
        br = rr; bc = w - rr * (rr + 1) / 2;
    };

    if constexpr (MODE == 0) {
        run_tile(work / nbx, work % nbx, K, true);
    } else if constexpr (MODE == 1) {
        int br, bc;
        tri(work, br, bc);
        run_tile(br, bc, K, true);
        const int e = work >> 4;
        if ((work & 15) == 8 && nwg + e < totj) {
            tri(nwg + e, br, bc);
            run_tile(br, bc, K, false);
        }
    } else {
        const int chunk = work >> 4;
        const int lo    = work & 15;
        const int col   = work & 7;
        const int row   = (lo < 8) ? chunk : 15 - chunk;
        run_tile(row, col, (row + 1) * BM, true);
    }
}

// ---- causal row softmax: bf16 scores in, bf16 P out, LDS-cached single read ----
__device__ __forceinline__ float waveMax(float v) {
#pragma unroll
    for (int o = 32; o > 0; o >>= 1) v = fmaxf(v, __shfl_xor(v, o, 64));
    return v;
}
__device__ __forceinline__ float waveSum(float v) {
#pragma unroll
    for (int o = 32; o > 0; o >>= 1) v += __shfl_xor(v, o, 64);
    return v;
}

__global__ __launch_bounds__(256)
void softmax_causal(const unsigned short* __restrict__ S, unsigned short* __restrict__ P,
                    int Slen) {
    __shared__ float e[2048];
    __shared__ float red[4];
    long long row = blockIdx.x;                 // b*Slen + q
    int q = (int)(row % Slen);
    const unsigned short* srow = S + row * (long long)Slen;
    unsigned short* prow = P + row * (long long)Slen;
    int len = q + 1;
    int t = threadIdx.x;

    int n8 = len >> 3;
    float mx = -3.0e38f;
    for (int i = t; i < n8; i += 256) {
        uint4 v = reinterpret_cast<const uint4*>(srow)[i];
        float f0 = __uint_as_float(v.x << 16), f1 = __uint_as_float(v.x & 0xffff0000u);
        float f2 = __uint_as_float(v.y << 16), f3 = __uint_as_float(v.y & 0xffff0000u);
        float f4 = __uint_as_float(v.z << 16), f5 = __uint_as_float(v.z & 0xffff0000u);
        float f6 = __uint_as_float(v.w << 16), f7 = __uint_as_float(v.w & 0xffff0000u);
        e[8 * i + 0] = f0; e[8 * i + 1] = f1; e[8 * i + 2] = f2; e[8 * i + 3] = f3;
        e[8 * i + 4] = f4; e[8 * i + 5] = f5; e[8 * i + 6] = f6; e[8 * i + 7] = f7;
        mx = fmaxf(mx, fmaxf(fmaxf(fmaxf(f0, f1), fmaxf(f2, f3)),
                             fmaxf(fmaxf(f4, f5), fmaxf(f6, f7))));
    }
    if (t < (len & 7)) {
        float v = bf2f(srow[n8 * 8 + t]);
        e[n8 * 8 + t] = v;
        mx = fmaxf(mx, v);
    }
    mx = waveMax(mx);
    if ((t & 63) == 0) red[t >> 6] = mx;
    __syncthreads();
    mx = fmaxf(fmaxf(red[0], red[1]), fmaxf(red[2], red[3]));

    float sum = 0.f;
    for (int k = t; k < len; k += 256) {
        float v = __expf(e[k] - mx);
        e[k] = v;
        sum += v;
    }
    sum = waveSum(sum);
    __syncthreads();
    if ((t & 63) == 0) red[t >> 6] = sum;
    __syncthreads();
    sum = red[0] + red[1] + red[2] + red[3];
    float inv = 1.0f / sum;

    int wlim = ((q >> 7) + 1) << 7;             // PX (BM=128) reads only k < roundup(len,128)
    __syncthreads();
    for (int i = t; i < (wlim >> 2); i += 256) {
        int k = 4 * i;
        ushort4 o;
        o.x = (k + 0 < len) ? f2bf(e[k + 0] * inv) : (unsigned short)0;
        o.y = (k + 1 < len) ? f2bf(e[k + 1] * inv) : (unsigned short)0;
        o.z = (k + 2 < len) ? f2bf(e[k + 2] * inv) : (unsigned short)0;
        o.w = (k + 3 < len) ? f2bf(e[k + 3] * inv) : (unsigned short)0;
        reinterpret_cast<ushort4*>(prow)[i] = o;
    }
}

extern "C" void kernel_launch(void* const* d_in, const int* in_sizes, int n_in,
                              void* d_out, int out_size, void* d_ws, size_t ws_size,
                              hipStream_t stream) {
    const int B = 4, S = 2048, D = 1024;
    const float* X  = (const float*)d_in[0];
    const float* Wq = (const float*)d_in[1];
    const float* Wk = (const float*)d_in[2];
    const float* Wv = (const float*)d_in[3];
    float* out = (float*)d_out;

    char* ws = (char*)d_ws;
    unsigned short* Xb    = (unsigned short*)ws; ws += (size_t)B * S * D * 2;
    unsigned short* XbT   = (unsigned short*)ws; ws += (size_t)B * D * S * 2;  // [b][e][s]
    unsigned short* WqT   = (unsigned short*)ws; ws += (size_t)D * D * 2;      // [i][e]
    unsigned short* WkT   = (unsigned short*)ws; ws += (size_t)D * D * 2;      // [j][e]
    unsigned short* Wvb   = (unsigned short*)ws; ws += (size_t)D * D * 2;      // [e][i]
    unsigned short* MTb   = (unsigned short*)ws; ws += (size_t)D * D * 2;      // MT[j][i]
    unsigned short* XMb   = (unsigned short*)ws; ws += (size_t)B * S * D * 2;  // X*M
    unsigned short* PXb   = (unsigned short*)ws; ws += (size_t)B * S * D * 2;  // P*X
    unsigned short* Sc    = (unsigned short*)ws; ws += (size_t)B * S * S * 2;  // bf16 scores
    unsigned short* P     = (unsigned short*)ws; ws += (size_t)B * S * S * 2;
    float*          Mpart = (float*)ws;          ws += (size_t)4 * D * D * 4;  // split-K partials

    // 1) convert + transposes in one dispatch
    convt_k<<<dim3(16, 32, 7), 256, 0, stream>>>(X, Wq, Wk, Wv, Xb, XbT, WqT, WkT, Wvb);

    dim3 blk(256);
    // 2) MT = Wk^T * Wq, split-K over 4 chunks of 256 (z = chunk; +z*256 shifts k-window)
    gemm8<float, 0><<<dim3(8, 8, 4), blk, 0, stream>>>(
        WkT, WqT, Mpart, D, D, D, 256, 256, 256, (long long)D * D, 1.0f, 0);
    reduce4_k<<<1024, 256, 0, stream>>>(Mpart, MTb, D * D / 4);

    // 3) XM = Xb * M  (NT with B = MT): grid (8,64,1) = 512 blocks
    gemm8<unsigned short, 0><<<dim3(8, 64, 1), blk, 0, stream>>>(
        Xb, MTb, XMb, D, D, D, D, 0, 0, 0, 1.0f, 0);

    // 4) scores = (XM * Xb^T)/32 as bf16 : 136 tri-tiles/batch over 128 blocks
    gemm8<unsigned short, 1><<<dim3(8, 16, B), blk, 0, stream>>>(
        XMb, Xb, Sc, D, D, S, D, (long long)S * D, (long long)S * D, (long long)S * S,
        0.03125f, 136);

    // 5) causal softmax -> P (bf16, zero-padded to 128)
    softmax_causal<<<B * S, 256, 0, stream>>>(Sc, P, S);

    // 6) PX = P * Xb (causal KLIM, balanced rows): A=P, B=XbT
    gemm8<unsigned short, 3><<<dim3(8, 16, B), blk, 0, stream>>>(
        P, XbT, PXb, S, S, D, S, (long long)S * S, (long long)D * S, (long long)S * D,
        1.0f, 0);

    // 7) out = PX * Wv^T : grid (8,64,1) = 512 blocks, fp32 out
    gemm8<float, 0><<<dim3(8, 64, 1), blk, 0, stream>>>(
        PXb, Wvb, out, D, D, D, D, 0, 0, 0, 1.0f, 0);
}

// Round 13
// 163.316 us; speedup vs baseline: 1.2467x; 1.0380x over previous
//
#include <hip/hip_runtime.h>
#include <stdint.h>
#include <math.h>

typedef __attribute__((ext_vector_type(8))) __bf16 bf16x8;
typedef __attribute__((ext_vector_type(4))) float f32x4;

__device__ __forceinline__ unsigned short f2bf(float f) {
    unsigned u = __float_as_uint(f);
    u += 0x7FFF + ((u >> 16) & 1);
    return (unsigned short)(u >> 16);
}
__device__ __forceinline__ float bf2f(unsigned short u) {
    return __uint_as_float((unsigned)u << 16);
}

// ---- convert / transpose / zero: z=0..3 X->Xb, z=4 Wq->WqT, z=5 Wk->WkT,
// ---- z=6 Wv->Wvb (plain), z=7 zero-fill d_out (needed for PV atomics) ----
__global__ __launch_bounds__(256)
void convt_k(const float* __restrict__ X, const float* __restrict__ Wq,
             const float* __restrict__ Wk, const float* __restrict__ Wv,
             unsigned short* __restrict__ Xb, unsigned short* __restrict__ WqT,
             unsigned short* __restrict__ WkT, unsigned short* __restrict__ Wvb,
             float* __restrict__ outz) {
    const int S = 2048, D = 1024;
    const int z = blockIdx.z;
    const int t = threadIdx.x;
    if (z == 7) {                                   // zero d_out: 8.4M floats
        const int n4 = 4 * S * D / 4 * 4 / 4;       // 2.1M float4... (B*S*D/4)
        int gid = (blockIdx.y * 16 + blockIdx.x) * 256 + t;
        int stride = 512 * 256;
        float4 zz = (float4){0.f, 0.f, 0.f, 0.f};
        for (int i = gid; i < 4 * S * D / 4; i += stride)
            reinterpret_cast<float4*>(outz)[i] = zz;
        return;
    }
    const float* src;
    unsigned short* dstP = nullptr;
    unsigned short* dstT = nullptr;
    int rows;
    if (z < 4)      { src = X + (size_t)z * S * D; dstP = Xb + (size_t)z * S * D; rows = S; }
    else if (z == 4){ src = Wq; dstT = WqT; rows = D; }
    else if (z == 5){ src = Wk; dstT = WkT; rows = D; }
    else            { src = Wv; dstP = Wvb; rows = D; }
    const int r0 = blockIdx.y * 64, c0 = blockIdx.x * 64;
    if (r0 >= rows) return;

    __shared__ float tile[64][65];
    const int tr = t >> 4;
    const int tc4 = t & 15;
#pragma unroll
    for (int p = 0; p < 4; ++p) {
        int r = p * 16 + tr;
        float4 v = *reinterpret_cast<const float4*>(&src[(size_t)(r0 + r) * 1024 + c0 + tc4 * 4]);
        if (dstP) {
            ushort4 o; o.x = f2bf(v.x); o.y = f2bf(v.y); o.z = f2bf(v.z); o.w = f2bf(v.w);
            *reinterpret_cast<ushort4*>(&dstP[(size_t)(r0 + r) * 1024 + c0 + tc4 * 4]) = o;
        }
        if (dstT) {
            tile[r][tc4 * 4 + 0] = v.x; tile[r][tc4 * 4 + 1] = v.y;
            tile[r][tc4 * 4 + 2] = v.z; tile[r][tc4 * 4 + 3] = v.w;
        }
    }
    if (!dstT) return;
    __syncthreads();
#pragma unroll
    for (int p = 0; p < 4; ++p) {
        int c = p * 16 + tr;
        ushort4 o;
        o.x = f2bf(tile[tc4 * 4 + 0][c]);
        o.y = f2bf(tile[tc4 * 4 + 1][c]);
        o.z = f2bf(tile[tc4 * 4 + 2][c]);
        o.w = f2bf(tile[tc4 * 4 + 3][c]);
        *reinterpret_cast<ushort4*>(&dstT[(size_t)(c0 + c) * 1024 + r0 + tc4 * 4]) = o;
    }
}

__global__ __launch_bounds__(256)
void reduce4_k(const float* __restrict__ p, unsigned short* __restrict__ o, int n4) {
    const int slab = 1024 * 1024 / 4;
    int i = blockIdx.x * blockDim.x + threadIdx.x;
    int stride = gridDim.x * blockDim.x;
    for (; i < n4; i += stride) {
        float4 a = reinterpret_cast<const float4*>(p)[i];
        float4 b = reinterpret_cast<const float4*>(p)[i + slab];
        float4 c = reinterpret_cast<const float4*>(p)[i + 2 * slab];
        float4 d = reinterpret_cast<const float4*>(p)[i + 3 * slab];
        ushort4 u;
        u.x = f2bf(a.x + b.x + c.x + d.x);
        u.y = f2bf(a.y + b.y + c.y + d.y);
        u.z = f2bf(a.z + b.z + c.z + d.z);
        u.w = f2bf(a.w + b.w + c.w + d.w);
        reinterpret_cast<ushort4*>(o)[i] = u;
    }
}

__device__ __forceinline__ void gload16(const unsigned short* g, unsigned short* l) {
    __builtin_amdgcn_global_load_lds(
        (const __attribute__((address_space(1))) unsigned int*)g,
        (__attribute__((address_space(3))) unsigned int*)l, 16, 0, 0);
}

// ===== shared 128x128 BK=64 tile core (r9/r11/r12 proven; counted vmcnt, XOR swz) =====
template <typename CT, bool ATOMIC>
__device__ __forceinline__ void core_tile(
    const unsigned short* __restrict__ A, const unsigned short* __restrict__ B,
    CT* __restrict__ C, int lda, int ldb, int ldc,
    int m0, int n0, int kst, int nk, float scale, bool first,
    unsigned short* AsB, unsigned short* BsB)
{
    const int t    = threadIdx.x;
    const int lane = t & 63;
    const int wid  = t >> 6;
    const int wm   = wid >> 1, wn = wid & 1;
    const int rsel = lane & 15;
    const int gsel = lane >> 4;
    const int srow = t >> 3;
    const int swz  = ((t & 7) ^ (srow & 7)) * 8;

    f32x4 acc[4][4];
#pragma unroll
    for (int m = 0; m < 4; ++m)
#pragma unroll
        for (int n = 0; n < 4; ++n) acc[m][n] = (f32x4){0.f, 0.f, 0.f, 0.f};

    const unsigned short* gpA[4];
    const unsigned short* gpB[4];
#pragma unroll
    for (int i = 0; i < 4; ++i) {
        gpA[i] = A + (long long)(m0 + srow + 32 * i) * lda + kst * 64 + swz;
        gpB[i] = B + (long long)(n0 + srow + 32 * i) * ldb + kst * 64 + swz;
    }

    auto stage = [&](int buf) {
#pragma unroll
        for (int i = 0; i < 4; ++i)
            gload16(gpA[i], &AsB[buf * 8192 + i * 2048 + t * 8]);
#pragma unroll
        for (int i = 0; i < 4; ++i)
            gload16(gpB[i], &BsB[buf * 8192 + i * 2048 + t * 8]);
#pragma unroll
        for (int i = 0; i < 4; ++i) { gpA[i] += 64; gpB[i] += 64; }
    };

    if (!first) {                            // protect LDS from previous job's readers
        __builtin_amdgcn_s_barrier();
        __builtin_amdgcn_sched_barrier(0);
    }
    stage(0);

    for (int kt = 0; kt < nk; ++kt) {
        const int c = kt & 1;
        __builtin_amdgcn_s_barrier();
        __builtin_amdgcn_sched_barrier(0);
        if (kt + 1 < nk) {
            stage(c ^ 1);
            asm volatile("s_waitcnt vmcnt(8)" ::: "memory");
        } else {
            asm volatile("s_waitcnt vmcnt(0)" ::: "memory");
        }
        __builtin_amdgcn_s_barrier();
        __builtin_amdgcn_sched_barrier(0);

        bf16x8 aF[4][2], bF[4][2];
#pragma unroll
        for (int m = 0; m < 4; ++m)
#pragma unroll
            for (int ks = 0; ks < 2; ++ks) {
                int r  = wm * 64 + m * 16 + rsel;
                int cc = ks * 4 + gsel;
                aF[m][ks] = *reinterpret_cast<const bf16x8*>(
                    &AsB[c * 8192 + r * 64 + ((cc ^ (r & 7)) * 8)]);
            }
#pragma unroll
        for (int n = 0; n < 4; ++n)
#pragma unroll
            for (int ks = 0; ks < 2; ++ks) {
                int rb = wn * 64 + n * 16 + rsel;
                int cc = ks * 4 + gsel;
                bF[n][ks] = *reinterpret_cast<const bf16x8*>(
                    &BsB[c * 8192 + rb * 64 + ((cc ^ (rb & 7)) * 8)]);
            }

        __builtin_amdgcn_s_setprio(1);
#pragma unroll
        for (int m = 0; m < 4; ++m)
#pragma unroll
            for (int n = 0; n < 4; ++n)
#pragma unroll
                for (int ks = 0; ks < 2; ++ks)
                    acc[m][n] = __builtin_amdgcn_mfma_f32_16x16x32_bf16(
                        aF[m][ks], bF[n][ks], acc[m][n], 0, 0, 0);
        __builtin_amdgcn_s_setprio(0);
    }

    // epilogue: D[row][col], col = lane&15, row = (lane>>4)*4 + i (m89-verified)
    const int rowl = gsel * 4;
#pragma unroll
    for (int m = 0; m < 4; ++m)
#pragma unroll
        for (int n = 0; n < 4; ++n)
#pragma unroll
            for (int i = 0; i < 4; ++i) {
                int r  = m0 + wm * 64 + m * 16 + rowl + i;
                int cI = n0 + wn * 64 + n * 16 + rsel;
                float v = acc[m][n][i] * scale;
                if constexpr (sizeof(CT) == 2)
                    ((unsigned short*)C)[(long long)r * ldc + cI] = f2bf(v);
                else if constexpr (ATOMIC)
                    unsafeAtomicAdd((float*)&C[(long long)r * ldc + cI], v);
                else
                    ((float*)C)[(long long)r * ldc + cI] = v;
            }
}

__device__ __forceinline__ void tri_decode(int w, int& br, int& bc) {
    int rr = (int)((sqrtf(8.0f * (float)w + 1.0f) - 1.0f) * 0.5f);
    while ((rr + 1) * (rr + 2) / 2 <= w) ++rr;
    while (rr * (rr + 1) / 2 > w) --rr;
    br = rr; bc = w - rr * (rr + 1) / 2;
}

// dense MODE0 GEMM (XM, M1): XCD-remapped uniform grid
template <typename CT>
__global__ __launch_bounds__(256, 2)
void gemm0(const unsigned short* __restrict__ A, const unsigned short* __restrict__ B,
           CT* __restrict__ C, int lda, int ldb, int ldc, int K,
           long long sA, long long sB, long long sC, float scale)
{
    __shared__ unsigned short As[2 * 8192];
    __shared__ unsigned short Bs[2 * 8192];
    const int nbx = gridDim.x;
    const int nwg = nbx * gridDim.y;
    const int orig = blockIdx.y * nbx + blockIdx.x;
    const int q8 = nwg >> 3, r8 = nwg & 7;
    const int xcd = orig & 7, idx = orig >> 3;
    const int work = (xcd < r8 ? xcd * (q8 + 1) : r8 * (q8 + 1) + (xcd - r8) * q8) + idx;
    core_tile<CT, false>(A + (long long)blockIdx.z * sA, B + (long long)blockIdx.z * sB,
                         C + (long long)blockIdx.z * sC, lda, ldb, ldc,
                         (work / nbx) * 128, (work % nbx) * 128, 0, K >> 6, scale, true,
                         As, Bs);
}

// merged {scores tri 544 tiles as 480 singles + 32 diag-pairs} + {Vt 512} = 1024 jobs
__global__ __launch_bounds__(256, 2)
void gemm_mrg(const unsigned short* __restrict__ XM, const unsigned short* __restrict__ Xb,
              unsigned short* __restrict__ Sc, const unsigned short* __restrict__ Wv,
              unsigned short* __restrict__ Vt)
{
    const int S = 2048, D = 1024;
    const long long SD = (long long)S * D, SS = (long long)S * S, DS = (long long)D * S;
    __shared__ unsigned short As[2 * 8192];
    __shared__ unsigned short Bs[2 * 8192];
    const int orig = blockIdx.x;
    const int work = (orig & 7) * 128 + (orig >> 3);     // nwg=1024, bijective
    const int xcdc = work >> 7, idx = work & 127;

    if (idx < 4) {
        // diagonal pair: 2 diag score tiles, 32 steps total (placed first per chunk)
        int d = xcdc * 4 + idx;                          // 0..31
        int b = d >> 3, dp = d & 7;
        const unsigned short* A = XM + b * SD;
        const unsigned short* B = Xb + b * SD;
        unsigned short* C = Sc + b * SS;
        core_tile<unsigned short, false>(A, B, C, D, D, S,
            (2 * dp) * 128, (2 * dp) * 128, 0, 16, 0.03125f, true, As, Bs);
        core_tile<unsigned short, false>(A, B, C, D, D, S,
            (2 * dp + 1) * 128, (2 * dp + 1) * 128, 0, 16, 0.03125f, false, As, Bs);
    } else {
        int j = xcdc * 124 + (idx - 4);                  // 0..991
        if (j < 480) {                                   // off-diagonal score tile
            int b = j / 120, tt = j % 120;
            int rr, cc;
            tri_decode(tt, rr, cc);                      // rr(rr+1)/2 <= tt
            int br = rr + 1, bc = tt - rr * (rr + 1) / 2;  // strict lower triangle
            core_tile<unsigned short, false>(XM + b * SD, Xb + b * SD, Sc + b * SS,
                D, D, S, br * 128, bc * 128, 0, 16, 0.03125f, true, As, Bs);
        } else {                                         // Vt job
            int v = j - 480;                             // 0..511
            int b = v >> 7, u = v & 127;
            int r = u >> 4, c = u & 15;
            core_tile<unsigned short, false>(Wv, Xb + b * SD, Vt + b * DS,
                D, D, S, r * 128, c * 128, 0, 16, 1.0f, true, As, Bs);
        }
    }
}

// PV with split-K balance: rows 0-7 direct (256 jobs), rows 8-15 k-halved atomic (512)
__global__ __launch_bounds__(256, 2)
void gemm_pv(const unsigned short* __restrict__ P, const unsigned short* __restrict__ Vt,
             float* __restrict__ out)
{
    const int S = 2048, D = 1024;
    const long long SS = (long long)S * S, DS = (long long)D * S, SD = (long long)S * D;
    __shared__ unsigned short As[2 * 8192];
    __shared__ unsigned short Bs[2 * 8192];
    const int orig = blockIdx.x;
    const int work = (orig & 7) * 96 + (orig >> 3);      // nwg=768, bijective
    if (work < 512) {                                    // type B: rows 8-15, k-half, atomic
        int b = work >> 7, u = work & 127;
        int r = 8 + (u >> 4);
        int rest = u & 15;
        int c = rest >> 1, h = rest & 1;
        int nk = r + 1;                                  // steps per half
        core_tile<float, true>(P + b * SS, Vt + b * DS, out + b * SD,
            S, S, D, r * 128, c * 128, h * nk, nk, 1.0f, true, As, Bs);
    } else {                                             // type A: rows 0-7, direct
        int a = work - 512;
        int b = a >> 6, u = a & 63;
        int r = u >> 3, c = u & 7;
        core_tile<float, false>(P + b * SS, Vt + b * DS, out + b * SD,
            S, S, D, r * 128, c * 128, 0, 2 * (r + 1), 1.0f, true, As, Bs);
    }
}

// ---- causal row softmax: bf16 scores in, bf16 P out ----
__device__ __forceinline__ float waveMax(float v) {
#pragma unroll
    for (int o = 32; o > 0; o >>= 1) v = fmaxf(v, __shfl_xor(v, o, 64));
    return v;
}
__device__ __forceinline__ float waveSum(float v) {
#pragma unroll
    for (int o = 32; o > 0; o >>= 1) v += __shfl_xor(v, o, 64);
    return v;
}

__global__ __launch_bounds__(256)
void softmax_causal(const unsigned short* __restrict__ S, unsigned short* __restrict__ P,
                    int Slen) {
    __shared__ float e[2048];
    __shared__ float red[4];
    long long row = blockIdx.x;
    int q = (int)(row % Slen);
    const unsigned short* srow = S + row * (long long)Slen;
    unsigned short* prow = P + row * (long long)Slen;
    int len = q + 1;
    int t = threadIdx.x;

    int n8 = len >> 3;
    float mx = -3.0e38f;
    for (int i = t; i < n8; i += 256) {
        uint4 v = reinterpret_cast<const uint4*>(srow)[i];
        float f0 = __uint_as_float(v.x << 16), f1 = __uint_as_float(v.x & 0xffff0000u);
        float f2 = __uint_as_float(v.y << 16), f3 = __uint_as_float(v.y & 0xffff0000u);
        float f4 = __uint_as_float(v.z << 16), f5 = __uint_as_float(v.z & 0xffff0000u);
        float f6 = __uint_as_float(v.w << 16), f7 = __uint_as_float(v.w & 0xffff0000u);
        e[8 * i + 0] = f0; e[8 * i + 1] = f1; e[8 * i + 2] = f2; e[8 * i + 3] = f3;
        e[8 * i + 4] = f4; e[8 * i + 5] = f5; e[8 * i + 6] = f6; e[8 * i + 7] = f7;
        mx = fmaxf(mx, fmaxf(fmaxf(fmaxf(f0, f1), fmaxf(f2, f3)),
                             fmaxf(fmaxf(f4, f5), fmaxf(f6, f7))));
    }
    if (t < (len & 7)) {
        float v = bf2f(srow[n8 * 8 + t]);
        e[n8 * 8 + t] = v;
        mx = fmaxf(mx, v);
    }
    mx = waveMax(mx);
    if ((t & 63) == 0) red[t >> 6] = mx;
    __syncthreads();
    mx = fmaxf(fmaxf(red[0], red[1]), fmaxf(red[2], red[3]));

    float sum = 0.f;
    for (int k = t; k < len; k += 256) {
        float v = __expf(e[k] - mx);
        e[k] = v;
        sum += v;
    }
    sum = waveSum(sum);
    __syncthreads();
    if ((t & 63) == 0) red[t >> 6] = sum;
    __syncthreads();
    sum = red[0] + red[1] + red[2] + red[3];
    float inv = 1.0f / sum;

    int wlim = ((q >> 7) + 1) << 7;             // PV (BM=128) reads only k < roundup(len,128)
    __syncthreads();
    for (int i = t; i < (wlim >> 2); i += 256) {
        int k = 4 * i;
        ushort4 o;
        o.x = (k + 0 < len) ? f2bf(e[k + 0] * inv) : (unsigned short)0;
        o.y = (k + 1 < len) ? f2bf(e[k + 1] * inv) : (unsigned short)0;
        o.z = (k + 2 < len) ? f2bf(e[k + 2] * inv) : (unsigned short)0;
        o.w = (k + 3 < len) ? f2bf(e[k + 3] * inv) : (unsigned short)0;
        reinterpret_cast<ushort4*>(prow)[i] = o;
    }
}

extern "C" void kernel_launch(void* const* d_in, const int* in_sizes, int n_in,
                              void* d_out, int out_size, void* d_ws, size_t ws_size,
                              hipStream_t stream) {
    const int B = 4, S = 2048, D = 1024;
    const float* X  = (const float*)d_in[0];
    const float* Wq = (const float*)d_in[1];
    const float* Wk = (const float*)d_in[2];
    const float* Wv = (const float*)d_in[3];
    float* out = (float*)d_out;

    char* ws = (char*)d_ws;
    unsigned short* Xb    = (unsigned short*)ws; ws += (size_t)B * S * D * 2;
    unsigned short* WqT   = (unsigned short*)ws; ws += (size_t)D * D * 2;   // [i][e]
    unsigned short* WkT   = (unsigned short*)ws; ws += (size_t)D * D * 2;   // [j][e]
    unsigned short* Wvb   = (unsigned short*)ws; ws += (size_t)D * D * 2;   // [e][i]
    unsigned short* MTb   = (unsigned short*)ws; ws += (size_t)D * D * 2;   // (Wk^T Wq)^T-ish
    unsigned short* XMb   = (unsigned short*)ws; ws += (size_t)B * S * D * 2;
    unsigned short* Vt    = (unsigned short*)ws; ws += (size_t)B * D * S * 2;  // [b][e][s]
    unsigned short* Sc    = (unsigned short*)ws; ws += (size_t)B * S * S * 2;
    unsigned short* P     = (unsigned short*)ws; ws += (size_t)B * S * S * 2;
    float*          Mpart = (float*)ws;          ws += (size_t)4 * D * D * 4;

    // 1) converts + W transposes + zero d_out
    convt_k<<<dim3(16, 32, 8), 256, 0, stream>>>(X, Wq, Wk, Wv, Xb, WqT, WkT, Wvb, out);

    dim3 blk(256);
    // 2) MT = Wk^T * Wq, split-K (z = k-chunk of 256)
    gemm0<float><<<dim3(8, 8, 4), blk, 0, stream>>>(
        WkT, WqT, Mpart, D, D, D, 256, 256, 256, (long long)D * D, 1.0f);
    reduce4_k<<<1024, 256, 0, stream>>>(Mpart, MTb, D * D / 4);

    // 3) XM = Xb * M
    gemm0<unsigned short><<<dim3(8, 64, 1), blk, 0, stream>>>(
        Xb, MTb, XMb, D, D, D, D, 0, 0, 0, 1.0f);

    // 4) merged: scores (tri, /32, bf16) + Vt = Wv @ X^T -- 1024 uniform jobs
    gemm_mrg<<<dim3(1024, 1, 1), blk, 0, stream>>>(XMb, Xb, Sc, Wvb, Vt);

    // 5) causal softmax -> P
    softmax_causal<<<B * S, 256, 0, stream>>>(Sc, P, S);

    // 6) out = P @ Vt^T, split-K balanced (rows 8-15 atomic-halved)
    gemm_pv<<<dim3(768, 1, 1), blk, 0, stream>>>(P, Vt, out);
}